// Round 1
// baseline (12948.259 us; speedup 1.0000x reference)
//
#include <hip/hip_runtime.h>

#define D   128
#define OD  384   // 3*D output row stride
#define NK  25    // KS^2 kernels

// ---------------- edge preprocessing: counting sort of edge-corners by wi ----

__global__ __launch_bounds__(256) void count_kernel(const int* __restrict__ dstA,
    const float* __restrict__ attr, int E, int* __restrict__ deg, int* __restrict__ cnt) {
  __shared__ int lc[NK];
  int tid = threadIdx.x;
  if (tid < NK) lc[tid] = 0;
  __syncthreads();
  int e = blockIdx.x * 256 + tid;
  if (e < E) {
    atomicAdd(&deg[dstA[e]], 1);
    float v0 = attr[2 * e] * 4.0f;
    float v1 = attr[2 * e + 1] * 4.0f;
    int i0 = min(3, max(0, (int)v0));
    int i1 = min(3, max(0, (int)v1));
    atomicAdd(&lc[i0     + 5 * i1], 1);
    atomicAdd(&lc[i0 + 1 + 5 * i1], 1);
    atomicAdd(&lc[i0     + 5 * (i1 + 1)], 1);
    atomicAdd(&lc[i0 + 1 + 5 * (i1 + 1)], 1);
  }
  __syncthreads();
  if (tid < NK && lc[tid]) atomicAdd(&cnt[tid], lc[tid]);
}

__global__ void prefix_kernel(const int* __restrict__ cnt, int* __restrict__ offs,
                              int* __restrict__ cursor) {
  if (threadIdx.x == 0) {
    int acc = 0;
    for (int k = 0; k < NK; ++k) { offs[k] = acc; cursor[k] = acc; acc += cnt[k]; }
    offs[NK] = acc;
  }
}

__global__ __launch_bounds__(256) void fill_kernel(const int* __restrict__ srcA,
    const int* __restrict__ dstA, const float* __restrict__ attr, int E,
    int* __restrict__ cursor, int* __restrict__ eSrc, int* __restrict__ eDst,
    float* __restrict__ eB) {
  __shared__ int lcnt[NK], lbase[NK], lcur[NK];
  int tid = threadIdx.x;
  if (tid < NK) lcnt[tid] = 0;
  __syncthreads();
  int e = blockIdx.x * 256 + tid;
  int wi[4];
  float bw[4];
  bool act = (e < E);
  if (act) {
    float v0 = attr[2 * e] * 4.0f;
    float v1 = attr[2 * e + 1] * 4.0f;
    int i0 = min(3, max(0, (int)v0));
    int i1 = min(3, max(0, (int)v1));
    float f0 = v0 - (float)i0;
    float f1 = v1 - (float)i1;
    int q = 0;
#pragma unroll
    for (int b1 = 0; b1 < 2; ++b1)
#pragma unroll
      for (int b0 = 0; b0 < 2; ++b0) {
        wi[q] = (i0 + b0) + 5 * (i1 + b1);
        bw[q] = (b0 ? f0 : 1.0f - f0) * (b1 ? f1 : 1.0f - f1);
        atomicAdd(&lcnt[wi[q]], 1);
        ++q;
      }
  }
  __syncthreads();
  if (tid < NK) {
    lbase[tid] = lcnt[tid] ? atomicAdd(&cursor[tid], lcnt[tid]) : 0;
    lcur[tid] = 0;
  }
  __syncthreads();
  if (act) {
    int s = srcA[e], d = dstA[e];
#pragma unroll
    for (int q = 0; q < 4; ++q) {
      int pos = lbase[wi[q]] + atomicAdd(&lcur[wi[q]], 1);
      eSrc[pos] = s;
      eDst[pos] = d;
      eB[pos] = bw[q];
    }
  }
}

// ---------------- fp32 GEMM: Y[N,128] = X[N,128] @ Wk[128,128] -----------------
// 64x64 tile per block (grid.y selects col half), full K=128 staged in LDS.

__global__ __launch_bounds__(256) void gemm_xw_kernel(const float* __restrict__ X,
    const float* __restrict__ Wk, float* __restrict__ Y, int N) {
  __shared__ __align__(16) float As[128][68];  // [k][m], +4 pad keeps 16B align
  __shared__ __align__(16) float Bs[128][68];  // [k][n]
  const int tid = threadIdx.x;
  const int m0 = blockIdx.x * 64;
  const int n0 = blockIdx.y * 64;
#pragma unroll
  for (int p = 0; p < 8; ++p) {
    int r = (tid >> 5) + p * 8;
    int c = (tid & 31) * 4;
    int gr = m0 + r;
    float4 v = make_float4(0.f, 0.f, 0.f, 0.f);
    if (gr < N) v = *(const float4*)(X + (size_t)gr * D + c);
    As[c + 0][r] = v.x; As[c + 1][r] = v.y; As[c + 2][r] = v.z; As[c + 3][r] = v.w;
  }
#pragma unroll
  for (int p = 0; p < 8; ++p) {
    int kk = (tid >> 4) + p * 16;
    int c = (tid & 15) * 4;
    *(float4*)&Bs[kk][c] = *(const float4*)(Wk + kk * D + n0 + c);
  }
  __syncthreads();
  const int ty = tid >> 4, tx = tid & 15;
  float acc[4][4] = {};
#pragma unroll 16
  for (int kk = 0; kk < 128; ++kk) {
    float4 av = *(const float4*)&As[kk][ty * 4];
    float4 bv = *(const float4*)&Bs[kk][tx * 4];
    float a[4] = {av.x, av.y, av.z, av.w};
    float b[4] = {bv.x, bv.y, bv.z, bv.w};
#pragma unroll
    for (int i = 0; i < 4; ++i)
#pragma unroll
      for (int j = 0; j < 4; ++j)
        acc[i][j] = fmaf(a[i], b[j], acc[i][j]);
  }
#pragma unroll
  for (int i = 0; i < 4; ++i) {
    int gr = m0 + ty * 4 + i;
    if (gr < N)
      *(float4*)(Y + (size_t)gr * D + n0 + tx * 4) =
          make_float4(acc[i][0], acc[i][1], acc[i][2], acc[i][3]);
  }
}

// ---------------- scatter bucket k: agg[dst] += b * Xk[src] --------------------

__global__ __launch_bounds__(256) void scatter_kernel(const int* __restrict__ offs, int k,
    const int* __restrict__ eSrc, const int* __restrict__ eDst, const float* __restrict__ eB,
    const float* __restrict__ Xk, float* __restrict__ agg) {
  int s = offs[k];
  int total = (offs[k + 1] - s) << 5;  // 32 work items (4 channels each) per entry
  for (int g = blockIdx.x * 256 + threadIdx.x; g < total; g += gridDim.x * 256) {
    int ent = s + (g >> 5);
    int ch = (g & 31) << 2;
    int src = eSrc[ent];
    int dst = eDst[ent];
    float b = eB[ent];
    float4 v = *(const float4*)(Xk + (size_t)src * D + ch);
    float* o = agg + (size_t)dst * D + ch;
    atomicAdd(o + 0, b * v.x);
    atomicAdd(o + 1, b * v.y);
    atomicAdd(o + 2, b * v.z);
    atomicAdd(o + 3, b * v.w);
  }
}

// ---------------- per-row l2norm / finalize ------------------------------------

__global__ __launch_bounds__(256) void l2norm_x_kernel(const float* __restrict__ x,
                                                       float* __restrict__ out, int N) {
  int g = blockIdx.x * 256 + threadIdx.x;
  int n = g >> 6, lane = g & 63;
  if (n >= N) return;
  float2 v = *(const float2*)(x + (size_t)n * D + lane * 2);
  float ss = v.x * v.x + v.y * v.y;
#pragma unroll
  for (int m = 1; m < 64; m <<= 1) ss += __shfl_xor(ss, m, 64);
  float r = 1.0f / fmaxf(sqrtf(ss), 1e-12f);
  *(float2*)(out + (size_t)n * OD + lane * 2) = make_float2(v.x * r, v.y * r);
}

__global__ __launch_bounds__(256) void finalize_kernel(const float* __restrict__ agg,
    const int* __restrict__ deg, const float* __restrict__ bias, float* __restrict__ out,
    float* __restrict__ xnext, int N) {
  int g = blockIdx.x * 256 + threadIdx.x;
  int n = g >> 6, lane = g & 63;
  if (n >= N) return;
  float inv = 1.0f / (float)max(deg[n], 1);
  float2 a = *(const float2*)(agg + (size_t)n * D + lane * 2);
  float2 b = *(const float2*)(bias + lane * 2);
  float h0 = a.x * inv + b.x;
  float h1 = a.y * inv + b.y;
  float ss = h0 * h0 + h1 * h1;
#pragma unroll
  for (int m = 1; m < 64; m <<= 1) ss += __shfl_xor(ss, m, 64);
  float r = 1.0f / fmaxf(sqrtf(ss), 1e-12f);
  *(float2*)(out + (size_t)n * OD + lane * 2) = make_float2(h0 * r, h1 * r);
  if (xnext)
    *(float2*)(xnext + (size_t)n * D + lane * 2) =
        make_float2(fmaxf(h0, 0.f), fmaxf(h1, 0.f));
}

// ---------------- launch -------------------------------------------------------

extern "C" void kernel_launch(void* const* d_in, const int* in_sizes, int n_in,
                              void* d_out, int out_size, void* d_ws, size_t ws_size,
                              hipStream_t stream) {
  const float* x    = (const float*)d_in[0];
  const int*   ei   = (const int*)d_in[1];
  const float* attr = (const float*)d_in[2];
  const float* w0   = (const float*)d_in[3];
  const float* b0   = (const float*)d_in[4];
  const float* w1   = (const float*)d_in[5];
  const float* b1   = (const float*)d_in[6];
  float* out = (float*)d_out;

  const int N = in_sizes[0] / D;
  const int E = in_sizes[1] / 2;
  const int* srcA = ei;
  const int* dstA = ei + E;

  // workspace carve (~116 MB total)
  char* p = (char*)d_ws;
  auto carve = [&](size_t bytes) -> char* {
    char* r = p;
    p += (bytes + 255) & ~(size_t)255;
    return r;
  };
  float* agg    = (float*)carve((size_t)N * D * 4);
  float* xtmp   = (float*)carve((size_t)N * D * 4);
  float* xkk    = (float*)carve((size_t)N * D * 4);
  int*   deg    = (int*)carve((size_t)N * 4);
  int*   cnt    = (int*)carve(128);
  int*   offs   = (int*)carve(128);
  int*   cursor = (int*)carve(128);
  int*   eSrc   = (int*)carve((size_t)E * 4 * 4);
  int*   eDst   = (int*)carve((size_t)E * 4 * 4);
  float* eB     = (float*)carve((size_t)E * 4 * 4);
  (void)ws_size; (void)n_in; (void)out_size;

  hipMemsetAsync(deg, 0, (size_t)N * 4, stream);
  hipMemsetAsync(cnt, 0, 128, stream);

  int eb = (E + 255) / 256;
  count_kernel<<<eb, 256, 0, stream>>>(dstA, attr, E, deg, cnt);
  prefix_kernel<<<1, 64, 0, stream>>>(cnt, offs, cursor);
  fill_kernel<<<eb, 256, 0, stream>>>(srcA, dstA, attr, E, cursor, eSrc, eDst, eB);

  int nb = (N * 64 + 255) / 256;
  l2norm_x_kernel<<<nb, 256, 0, stream>>>(x, out, N);

  dim3 ggrid((N + 63) / 64, 2);
  const float* xin = x;
  const float* Ws[2] = {w0, w1};
  const float* Bv[2] = {b0, b1};
  for (int layer = 0; layer < 2; ++layer) {
    hipMemsetAsync(agg, 0, (size_t)N * D * 4, stream);
    for (int k = 0; k < NK; ++k) {
      gemm_xw_kernel<<<ggrid, 256, 0, stream>>>(xin, Ws[layer] + (size_t)k * D * D, xkk, N);
      scatter_kernel<<<8192, 256, 0, stream>>>(offs, k, eSrc, eDst, eB, xkk, agg);
    }
    finalize_kernel<<<nb, 256, 0, stream>>>(agg, deg, Bv[layer], out + D * (layer + 1),
                                            layer == 0 ? xtmp : nullptr, N);
    xin = xtmp;
  }
}

// Round 2
// 2487.129 us; speedup vs baseline: 5.2061x; 5.2061x over previous
//
#include <hip/hip_runtime.h>

#define D   128
#define OD  384   // 3*D output row stride
#define NK  25    // KS^2 kernels

// ---------------- preprocessing: sort edges by dst --------------------------

__global__ __launch_bounds__(256) void deg_kernel(const int* __restrict__ dstA, int E,
                                                  int* __restrict__ deg) {
  int e = blockIdx.x * 256 + threadIdx.x;
  if (e < E) atomicAdd(&deg[dstA[e]], 1);
}

// exclusive scan over deg[N] -> base[N]; single block
__global__ __launch_bounds__(1024) void scan_kernel(const int* __restrict__ deg, int N,
                                                    int* __restrict__ base) {
  __shared__ int part[1024];
  int tid = threadIdx.x;
  int chunk = (N + 1023) / 1024;
  int s0 = min(N, tid * chunk), s1 = min(N, s0 + chunk);
  int sum = 0;
  for (int i = s0; i < s1; ++i) sum += deg[i];
  part[tid] = sum;
  __syncthreads();
  if (tid == 0) {
    int acc = 0;
    for (int i = 0; i < 1024; ++i) { int t = part[i]; part[i] = acc; acc += t; }
  }
  __syncthreads();
  int acc = part[tid];
  for (int i = s0; i < s1; ++i) { base[i] = acc; acc += deg[i]; }
}

__global__ __launch_bounds__(256) void fill_kernel(const int* __restrict__ srcA,
    const int* __restrict__ dstA, const float* __restrict__ attr, int E,
    const int* __restrict__ base, int* __restrict__ cursor,
    int* __restrict__ sSrc, unsigned int* __restrict__ sWi, float4* __restrict__ sBw) {
  int e = blockIdx.x * 256 + threadIdx.x;
  if (e >= E) return;
  int d = dstA[e];
  int pos = base[d] + atomicAdd(&cursor[d], 1);
  float v0 = attr[2 * e] * 4.0f;
  float v1 = attr[2 * e + 1] * 4.0f;
  int i0 = min(3, max(0, (int)v0));
  int i1 = min(3, max(0, (int)v1));
  float f0 = v0 - (float)i0;
  float f1 = v1 - (float)i1;
  sSrc[pos] = srcA[e];
  unsigned int w00 = (unsigned int)(i0 + 5 * i1);
  sWi[pos] = w00 | ((w00 + 1) << 5) | ((w00 + 5) << 10) | ((w00 + 6) << 15);
  sBw[pos] = make_float4((1.f - f0) * (1.f - f1), f0 * (1.f - f1),
                         (1.f - f0) * f1,         f0 * f1);
}

// ---------------- fp32 chunked GEMM: Xc[N, KC*128] = X @ W[kc0..kc0+KC) -------

__global__ __launch_bounds__(256) void gemm_chunk_kernel(const float* __restrict__ X,
    const float* __restrict__ Wc, float* __restrict__ Y, int N, int KCc) {
  __shared__ __align__(16) float As[128][68];
  __shared__ __align__(16) float Bs[128][68];
  const int tid = threadIdx.x;
  const int m0 = blockIdx.x * 64;
  const int kl = blockIdx.y >> 1;
  const int o0 = (blockIdx.y & 1) * 64;
  const float* Wk = Wc + (size_t)kl * D * D;
  const size_t ldY = (size_t)KCc * D;
#pragma unroll
  for (int p = 0; p < 8; ++p) {
    int r = (tid >> 5) + p * 8;
    int c = (tid & 31) * 4;
    int gr = m0 + r;
    float4 v = make_float4(0.f, 0.f, 0.f, 0.f);
    if (gr < N) v = *(const float4*)(X + (size_t)gr * D + c);
    As[c + 0][r] = v.x; As[c + 1][r] = v.y; As[c + 2][r] = v.z; As[c + 3][r] = v.w;
  }
#pragma unroll
  for (int p = 0; p < 8; ++p) {
    int kk = (tid >> 4) + p * 16;
    int c = (tid & 15) * 4;
    *(float4*)&Bs[kk][c] = *(const float4*)(Wk + kk * D + o0 + c);
  }
  __syncthreads();
  const int ty = tid >> 4, tx = tid & 15;
  float acc[4][4] = {};
#pragma unroll 16
  for (int kk = 0; kk < 128; ++kk) {
    float4 av = *(const float4*)&As[kk][ty * 4];
    float4 bv = *(const float4*)&Bs[kk][tx * 4];
    float a[4] = {av.x, av.y, av.z, av.w};
    float b[4] = {bv.x, bv.y, bv.z, bv.w};
#pragma unroll
    for (int i = 0; i < 4; ++i)
#pragma unroll
      for (int j = 0; j < 4; ++j)
        acc[i][j] = fmaf(a[i], b[j], acc[i][j]);
  }
#pragma unroll
  for (int i = 0; i < 4; ++i) {
    int gr = m0 + ty * 4 + i;
    if (gr < N)
      *(float4*)(Y + (size_t)gr * ldY + kl * D + o0 + tx * 4) =
          make_float4(acc[i][0], acc[i][1], acc[i][2], acc[i][3]);
  }
}

// ---------------- gather: one wave per dst, no atomics ------------------------

__global__ __launch_bounds__(256) void gather_kernel(const int* __restrict__ base,
    const int* __restrict__ deg, const int* __restrict__ sSrc,
    const unsigned int* __restrict__ sWi, const float4* __restrict__ sBw,
    const float* __restrict__ Xc, int KCc, int kc0, float* __restrict__ agg, int N,
    int firstChunk) {
  int wv = blockIdx.x * 4 + (threadIdx.x >> 6);
  int lane = threadIdx.x & 63;
  if (wv >= N) return;
  int s = base[wv];
  int n = deg[wv];
  float* arow = agg + (size_t)wv * D + lane * 2;
  float2 acc = firstChunk ? make_float2(0.f, 0.f) : *(const float2*)arow;
  for (int j = s; j < s + n; ++j) {
    int src = sSrc[j];
    unsigned int wim = sWi[j];
    float4 bw = sBw[j];
    const float* Xr = Xc + (size_t)src * ((size_t)KCc * D) + lane * 2;
    float b[4] = {bw.x, bw.y, bw.z, bw.w};
#pragma unroll
    for (int q = 0; q < 4; ++q) {
      int kl = (int)((wim >> (5 * q)) & 31u) - kc0;
      if ((unsigned)kl < (unsigned)KCc) {
        float2 v = *(const float2*)(Xr + (size_t)kl * D);
        acc.x = fmaf(b[q], v.x, acc.x);
        acc.y = fmaf(b[q], v.y, acc.y);
      }
    }
  }
  *(float2*)arow = acc;
}

// ---------------- per-row l2norm / finalize ------------------------------------

__global__ __launch_bounds__(256) void l2norm_x_kernel(const float* __restrict__ x,
                                                       float* __restrict__ out, int N) {
  int g = blockIdx.x * 256 + threadIdx.x;
  int n = g >> 6, lane = g & 63;
  if (n >= N) return;
  float2 v = *(const float2*)(x + (size_t)n * D + lane * 2);
  float ss = v.x * v.x + v.y * v.y;
#pragma unroll
  for (int m = 1; m < 64; m <<= 1) ss += __shfl_xor(ss, m, 64);
  float r = 1.0f / fmaxf(sqrtf(ss), 1e-12f);
  *(float2*)(out + (size_t)n * OD + lane * 2) = make_float2(v.x * r, v.y * r);
}

__global__ __launch_bounds__(256) void finalize_kernel(const float* __restrict__ agg,
    const int* __restrict__ deg, const float* __restrict__ bias, float* __restrict__ out,
    float* __restrict__ xnext, int N) {
  int g = blockIdx.x * 256 + threadIdx.x;
  int n = g >> 6, lane = g & 63;
  if (n >= N) return;
  float inv = 1.0f / (float)max(deg[n], 1);
  float2 a = *(const float2*)(agg + (size_t)n * D + lane * 2);
  float2 b = *(const float2*)(bias + lane * 2);
  float h0 = a.x * inv + b.x;
  float h1 = a.y * inv + b.y;
  float ss = h0 * h0 + h1 * h1;
#pragma unroll
  for (int m = 1; m < 64; m <<= 1) ss += __shfl_xor(ss, m, 64);
  float r = 1.0f / fmaxf(sqrtf(ss), 1e-12f);
  *(float2*)(out + (size_t)n * OD + lane * 2) = make_float2(h0 * r, h1 * r);
  if (xnext)
    *(float2*)(xnext + (size_t)n * D + lane * 2) =
        make_float2(fmaxf(h0, 0.f), fmaxf(h1, 0.f));
}

// ---------------- launch -------------------------------------------------------

extern "C" void kernel_launch(void* const* d_in, const int* in_sizes, int n_in,
                              void* d_out, int out_size, void* d_ws, size_t ws_size,
                              hipStream_t stream) {
  const float* x    = (const float*)d_in[0];
  const int*   ei   = (const int*)d_in[1];
  const float* attr = (const float*)d_in[2];
  const float* w0   = (const float*)d_in[3];
  const float* b0   = (const float*)d_in[4];
  const float* w1   = (const float*)d_in[5];
  const float* b1   = (const float*)d_in[6];
  float* out = (float*)d_out;

  const int N = in_sizes[0] / D;
  const int E = in_sizes[1] / 2;
  const int* srcA = ei;
  const int* dstA = ei + E;

  char* p = (char*)d_ws;
  auto carve = [&](size_t bytes) -> char* {
    char* r = p;
    p += (bytes + 255) & ~(size_t)255;
    return r;
  };
  float*        agg    = (float*)carve((size_t)N * D * 4);
  float*        xtmp   = (float*)carve((size_t)N * D * 4);
  int*          deg    = (int*)carve((size_t)N * 4);
  int*          base   = (int*)carve((size_t)N * 4);
  int*          cursor = (int*)carve((size_t)N * 4);
  int*          sSrc   = (int*)carve((size_t)E * 4);
  unsigned int* sWi    = (unsigned int*)carve((size_t)E * 4);
  float4*       sBw    = (float4*)carve((size_t)E * 16);
  size_t used = (size_t)(p - (char*)d_ws);
  size_t remain = (ws_size > used) ? (ws_size - used) : 0;
  int KC = (int)(remain / ((size_t)N * D * 4));
  if (KC > NK) KC = NK;
  if (KC < 1) KC = 1;
  float* Xc = (float*)carve((size_t)N * (size_t)KC * D * 4);
  (void)n_in; (void)out_size;

  hipMemsetAsync(deg, 0, (size_t)N * 4, stream);
  hipMemsetAsync(cursor, 0, (size_t)N * 4, stream);

  int eb = (E + 255) / 256;
  deg_kernel<<<eb, 256, 0, stream>>>(dstA, E, deg);
  scan_kernel<<<1, 1024, 0, stream>>>(deg, N, base);
  fill_kernel<<<eb, 256, 0, stream>>>(srcA, dstA, attr, E, base, cursor, sSrc, sWi, sBw);

  int nb = (N * 64 + 255) / 256;
  l2norm_x_kernel<<<nb, 256, 0, stream>>>(x, out, N);

  int gb = (N + 3) / 4;  // gather blocks: 4 waves per block, 1 wave per dst
  const float* xin = x;
  const float* Ws[2] = {w0, w1};
  const float* Bv[2] = {b0, b1};
  for (int layer = 0; layer < 2; ++layer) {
    int first = 1;
    for (int kc0 = 0; kc0 < NK; kc0 += KC) {
      int KCc = min(KC, NK - kc0);
      dim3 ggrid((N + 63) / 64, KCc * 2);
      gemm_chunk_kernel<<<ggrid, 256, 0, stream>>>(
          xin, Ws[layer] + (size_t)kc0 * D * D, Xc, N, KCc);
      gather_kernel<<<gb, 256, 0, stream>>>(base, deg, sSrc, sWi, sBw, Xc, KCc, kc0,
                                            agg, N, first);
      first = 0;
    }
    finalize_kernel<<<nb, 256, 0, stream>>>(agg, deg, Bv[layer], out + D * (layer + 1),
                                            layer == 0 ? xtmp : nullptr, N);
    xin = xtmp;
  }
}

// Round 3
// 997.204 us; speedup vs baseline: 12.9846x; 2.4941x over previous
//
#include <hip/hip_runtime.h>

#define D     128
#define OD    384   // 3*D output row stride
#define NK    25    // KS^2 kernels
#define KCMAX 13    // max k-chunk (LDS + workspace sizing)

typedef __attribute__((ext_vector_type(8))) short bf16x8;
typedef __attribute__((ext_vector_type(4))) float f32x4;
typedef const __attribute__((address_space(1))) void gv_t;
typedef __attribute__((address_space(3))) void lv_t;

__device__ inline unsigned short f2bf(float f) {
  unsigned int u = __float_as_uint(f);
  u += 0x7fffu + ((u >> 16) & 1u);
  return (unsigned short)(u >> 16);
}

// ---------------- preprocessing: sort edges by dst --------------------------

__global__ __launch_bounds__(256) void deg_kernel(const int* __restrict__ dstA, int E,
                                                  int* __restrict__ deg) {
  int e = blockIdx.x * 256 + threadIdx.x;
  if (e < E) atomicAdd(&deg[dstA[e]], 1);
}

__global__ __launch_bounds__(1024) void scan_kernel(const int* __restrict__ deg, int N,
                                                    int* __restrict__ base) {
  __shared__ int part[1024];
  int tid = threadIdx.x;
  int chunk = (N + 1023) / 1024;
  int s0 = min(N, tid * chunk), s1 = min(N, s0 + chunk);
  int sum = 0;
  for (int i = s0; i < s1; ++i) sum += deg[i];
  part[tid] = sum;
  __syncthreads();
  if (tid == 0) {
    int acc = 0;
    for (int i = 0; i < 1024; ++i) { int t = part[i]; part[i] = acc; acc += t; }
  }
  __syncthreads();
  int acc = part[tid];
  for (int i = s0; i < s1; ++i) { base[i] = acc; acc += deg[i]; }
}

__global__ __launch_bounds__(256) void fill_kernel(const int* __restrict__ srcA,
    const int* __restrict__ dstA, const float* __restrict__ attr, int E,
    const int* __restrict__ base, int* __restrict__ cursor,
    int* __restrict__ sSrc, unsigned int* __restrict__ sWi, float4* __restrict__ sBw) {
  int e = blockIdx.x * 256 + threadIdx.x;
  if (e >= E) return;
  int d = dstA[e];
  int pos = base[d] + atomicAdd(&cursor[d], 1);
  float v0 = attr[2 * e] * 4.0f;
  float v1 = attr[2 * e + 1] * 4.0f;
  int i0 = min(3, max(0, (int)v0));
  int i1 = min(3, max(0, (int)v1));
  float f0 = v0 - (float)i0;
  float f1 = v1 - (float)i1;
  sSrc[pos] = srcA[e];
  unsigned int w00 = (unsigned int)(i0 + 5 * i1);
  sWi[pos] = w00 | ((w00 + 1) << 5) | ((w00 + 5) << 10) | ((w00 + 6) << 15);
  sBw[pos] = make_float4((1.f - f0) * (1.f - f1), f0 * (1.f - f1),
                         (1.f - f0) * f1,         f0 * f1);
}

// WT[n][kk] = bf16(W[kk/128][kk%128][n]), kk = k*128+i flattened, per layer
__global__ __launch_bounds__(256) void wt_kernel(const float* __restrict__ W,
                                                 unsigned short* __restrict__ WT) {
  int idx = blockIdx.x * 256 + threadIdx.x;  // over 128*3200
  if (idx >= 128 * NK * D) return;
  int n = idx / (NK * D);
  int kk = idx - n * (NK * D);
  WT[idx] = f2bf(W[(size_t)kk * D + n]);
}

// ---------------- gather: G[dst, k-chunk, :] = sum b * x[src] (bf16 out) -----

__global__ __launch_bounds__(256) void gather_kernel(const int* __restrict__ base,
    const int* __restrict__ deg, const int* __restrict__ sSrc,
    const unsigned int* __restrict__ sWi, const float4* __restrict__ sBw,
    const float* __restrict__ X, unsigned short* __restrict__ Gc, int N, int KCc,
    int kc0) {
  __shared__ float lacc[4][KCMAX * D];
  int w = threadIdx.x >> 6, l = threadIdx.x & 63;
  int dst = blockIdx.x * 4 + w;
  if (dst >= N) return;
  float* A = lacc[w];
  for (int k = 0; k < KCc; ++k)
    *(float2*)(A + k * D + l * 2) = make_float2(0.f, 0.f);
  int s = base[dst], n = deg[dst];
  for (int j = s; j < s + n; ++j) {
    int src = sSrc[j];
    unsigned int wim = sWi[j];
    float4 bw = sBw[j];
    float2 xv = *(const float2*)(X + (size_t)src * D + l * 2);
    float b[4] = {bw.x, bw.y, bw.z, bw.w};
#pragma unroll
    for (int q = 0; q < 4; ++q) {
      int k = (int)((wim >> (5 * q)) & 31u) - kc0;
      if ((unsigned)k < (unsigned)KCc) {
        float* p = A + k * D + l * 2;
        p[0] = fmaf(b[q], xv.x, p[0]);
        p[1] = fmaf(b[q], xv.y, p[1]);
      }
    }
  }
  unsigned short* gr = Gc + (size_t)dst * ((size_t)KCc * D);
  for (int k = 0; k < KCc; ++k) {
    float2 v = *(const float2*)(A + k * D + l * 2);
    unsigned int pk = (unsigned int)f2bf(v.x) | ((unsigned int)f2bf(v.y) << 16);
    *(unsigned int*)(gr + k * D + l * 2) = pk;
  }
}

// ---------------- bf16 MFMA GEMM: Y[N,128] (+)= Gc[N,KCc*128] @ W[kchunk] ----
// 128x128 tile, 4 waves, BK=64, global_load_lds w/ pre-swizzled source (T2).

__global__ __launch_bounds__(256) void gemm_kernel(
    const unsigned short* __restrict__ G, const unsigned short* __restrict__ WT,
    float* __restrict__ Y, int N, int KCc, int kc0, int first) {
  __shared__ __attribute__((aligned(16))) char At[16384];
  __shared__ __attribute__((aligned(16))) char Bt[16384];
  const int tid = threadIdx.x;
  const int w = tid >> 6;
  const int l = tid & 63;
  const int m0 = blockIdx.x * 128;
  const size_t ldG = (size_t)KCc * 256;  // bytes per G row
  const size_t ldW = (size_t)NK * 256;   // 6400 bytes per WT row

  const int lrow = l >> 3;                       // row within 8-row group
  const int scol = ((l & 7) * 16) ^ (lrow << 4); // swizzled source column byte

  f32x4 acc[2][8];
#pragma unroll
  for (int mr = 0; mr < 2; ++mr)
#pragma unroll
    for (int nc = 0; nc < 8; ++nc) {
      if (first) {
        acc[mr][nc] = (f32x4){0.f, 0.f, 0.f, 0.f};
      } else {
        int col = nc * 16 + (l & 15);
#pragma unroll
        for (int j = 0; j < 4; ++j) {
          int row = m0 + w * 32 + mr * 16 + (l >> 4) * 4 + j;
          acc[mr][nc][j] = (row < N) ? Y[(size_t)row * D + col] : 0.f;
        }
      }
    }

  const int steps = KCc * 2;
  for (int kt = 0; kt < steps; ++kt) {
    __syncthreads();
#pragma unroll
    for (int i = 0; i < 4; ++i) {  // stage A: 8 G-rows per load
      int row = w * 32 + i * 8 + lrow;
      int node = m0 + row;
      if (node > N - 1) node = N - 1;
      const char* src = (const char*)G + (size_t)node * ldG + kt * 128 + scol;
      __builtin_amdgcn_global_load_lds((gv_t*)src, (lv_t*)(At + (w * 4 + i) * 1024),
                                       16, 0, 0);
    }
#pragma unroll
    for (int i = 0; i < 4; ++i) {  // stage B from WT (n-major)
      int nr = w * 32 + i * 8 + lrow;
      const char* src = (const char*)WT + (size_t)nr * ldW + kc0 * 256 + kt * 128 + scol;
      __builtin_amdgcn_global_load_lds((gv_t*)src, (lv_t*)(Bt + (w * 4 + i) * 1024),
                                       16, 0, 0);
    }
    __syncthreads();
#pragma unroll
    for (int ks = 0; ks < 2; ++ks) {
      int kb = ks * 64 + (l >> 4) * 16;
      bf16x8 a[2], b[8];
#pragma unroll
      for (int mr = 0; mr < 2; ++mr) {
        int r = w * 32 + mr * 16 + (l & 15);
        a[mr] = *(const bf16x8*)(At + r * 128 + (kb ^ ((r & 7) << 4)));
      }
#pragma unroll
      for (int nc = 0; nc < 8; ++nc) {
        int nr = nc * 16 + (l & 15);
        b[nc] = *(const bf16x8*)(Bt + nr * 128 + (kb ^ ((nr & 7) << 4)));
      }
#pragma unroll
      for (int mr = 0; mr < 2; ++mr)
#pragma unroll
        for (int nc = 0; nc < 8; ++nc)
          acc[mr][nc] =
              __builtin_amdgcn_mfma_f32_16x16x32_bf16(a[mr], b[nc], acc[mr][nc], 0, 0, 0);
    }
  }

#pragma unroll
  for (int mr = 0; mr < 2; ++mr)
#pragma unroll
    for (int nc = 0; nc < 8; ++nc) {
      int col = nc * 16 + (l & 15);
#pragma unroll
      for (int j = 0; j < 4; ++j) {
        int row = m0 + w * 32 + mr * 16 + (l >> 4) * 4 + j;
        if (row < N) Y[(size_t)row * D + col] = acc[mr][nc][j];
      }
    }
}

// ---------------- per-row l2norm / finalize ---------------------------------

__global__ __launch_bounds__(256) void l2norm_x_kernel(const float* __restrict__ x,
                                                       float* __restrict__ out, int N) {
  int g = blockIdx.x * 256 + threadIdx.x;
  int n = g >> 6, lane = g & 63;
  if (n >= N) return;
  float2 v = *(const float2*)(x + (size_t)n * D + lane * 2);
  float ss = v.x * v.x + v.y * v.y;
#pragma unroll
  for (int m = 1; m < 64; m <<= 1) ss += __shfl_xor(ss, m, 64);
  float r = 1.0f / fmaxf(sqrtf(ss), 1e-12f);
  *(float2*)(out + (size_t)n * OD + lane * 2) = make_float2(v.x * r, v.y * r);
}

__global__ __launch_bounds__(256) void finalize_kernel(const float* __restrict__ y,
    const int* __restrict__ deg, const float* __restrict__ bias, float* __restrict__ out,
    float* __restrict__ xnext, int N) {
  int g = blockIdx.x * 256 + threadIdx.x;
  int n = g >> 6, lane = g & 63;
  if (n >= N) return;
  float inv = 1.0f / (float)max(deg[n], 1);
  float2 a = *(const float2*)(y + (size_t)n * D + lane * 2);
  float2 b = *(const float2*)(bias + lane * 2);
  float h0 = a.x * inv + b.x;
  float h1 = a.y * inv + b.y;
  float ss = h0 * h0 + h1 * h1;
#pragma unroll
  for (int m = 1; m < 64; m <<= 1) ss += __shfl_xor(ss, m, 64);
  float r = 1.0f / fmaxf(sqrtf(ss), 1e-12f);
  *(float2*)(out + (size_t)n * OD + lane * 2) = make_float2(h0 * r, h1 * r);
  if (xnext)
    *(float2*)(xnext + (size_t)n * D + lane * 2) =
        make_float2(fmaxf(h0, 0.f), fmaxf(h1, 0.f));
}

// ---------------- launch -----------------------------------------------------

extern "C" void kernel_launch(void* const* d_in, const int* in_sizes, int n_in,
                              void* d_out, int out_size, void* d_ws, size_t ws_size,
                              hipStream_t stream) {
  const float* x    = (const float*)d_in[0];
  const int*   ei   = (const int*)d_in[1];
  const float* attr = (const float*)d_in[2];
  const float* w0   = (const float*)d_in[3];
  const float* b0   = (const float*)d_in[4];
  const float* w1   = (const float*)d_in[5];
  const float* b1   = (const float*)d_in[6];
  float* out = (float*)d_out;

  const int N = in_sizes[0] / D;
  const int E = in_sizes[1] / 2;
  const int* srcA = ei;
  const int* dstA = ei + E;

  char* p = (char*)d_ws;
  auto carve = [&](size_t bytes) -> char* {
    char* r = p;
    p += (bytes + 255) & ~(size_t)255;
    return r;
  };
  float*          xtmp   = (float*)carve((size_t)N * D * 4);
  float*          ygemm  = (float*)carve((size_t)N * D * 4);
  int*            deg    = (int*)carve((size_t)N * 4);
  int*            base   = (int*)carve((size_t)N * 4);
  int*            cursor = (int*)carve((size_t)N * 4);
  int*            sSrc   = (int*)carve((size_t)E * 4);
  unsigned int*   sWi    = (unsigned int*)carve((size_t)E * 4);
  float4*         sBw    = (float4*)carve((size_t)E * 16);
  unsigned short* WT0    = (unsigned short*)carve((size_t)128 * NK * D * 2);
  unsigned short* WT1    = (unsigned short*)carve((size_t)128 * NK * D * 2);
  size_t used = (size_t)(p - (char*)d_ws);
  size_t remain = (ws_size > used) ? (ws_size - used) : 0;
  int KCg = (int)(remain / ((size_t)N * D * 2));  // bf16 G bytes per k
  if (KCg > KCMAX) KCg = KCMAX;
  if (KCg < 1) KCg = 1;
  unsigned short* Gc = (unsigned short*)carve((size_t)N * (size_t)KCg * D * 2);
  (void)n_in; (void)out_size;

  hipMemsetAsync(deg, 0, (size_t)N * 4, stream);
  hipMemsetAsync(cursor, 0, (size_t)N * 4, stream);

  int eb = (E + 255) / 256;
  deg_kernel<<<eb, 256, 0, stream>>>(dstA, E, deg);
  scan_kernel<<<1, 1024, 0, stream>>>(deg, N, base);
  fill_kernel<<<eb, 256, 0, stream>>>(srcA, dstA, attr, E, base, cursor, sSrc, sWi, sBw);
  int wtb = (128 * NK * D + 255) / 256;
  wt_kernel<<<wtb, 256, 0, stream>>>(w0, WT0);
  wt_kernel<<<wtb, 256, 0, stream>>>(w1, WT1);

  int nb = (N * 64 + 255) / 256;
  l2norm_x_kernel<<<nb, 256, 0, stream>>>(x, out, N);

  int gbg = (N + 3) / 4;              // gather: 4 waves/block, wave per dst
  int gbm = (N + 127) / 128;          // gemm: 128-row tiles
  const float* xin = x;
  const float* Bv[2] = {b0, b1};
  const unsigned short* WTl[2] = {WT0, WT1};
  for (int layer = 0; layer < 2; ++layer) {
    int first = 1;
    for (int kc0 = 0; kc0 < NK; kc0 += KCg) {
      int KCc = min(KCg, NK - kc0);
      gather_kernel<<<gbg, 256, 0, stream>>>(base, deg, sSrc, sWi, sBw, xin, Gc, N,
                                             KCc, kc0);
      gemm_kernel<<<gbm, 256, 0, stream>>>(Gc, WTl[layer], ygemm, N, KCc, kc0, first);
      first = 0;
    }
    finalize_kernel<<<nb, 256, 0, stream>>>(ygemm, deg, Bv[layer], out + D * (layer + 1),
                                            layer == 0 ? xtmp : nullptr, N);
    xin = xtmp;
  }
}